// Round 1
// baseline (745969.092 us; speedup 1.0000x reference)
//
#include <hip/hip_runtime.h>

#define IDIM  64
#define HDIM  512
#define T_LEN 65536
#define NWG   64
#define NTHR  512

// Persistent state (re-initialized by lstm_init every call -> deterministic)
__device__ float    g_h1[2][HDIM];
__device__ float    g_h2[2][HDIM];
__device__ unsigned g_flag[NWG * 32];   // one 128B line per WG

__global__ void lstm_init() {
  int t = threadIdx.x;
  float* p1 = &g_h1[0][0];
  float* p2 = &g_h2[0][0];
  for (int e = t; e < 2 * HDIM; e += blockDim.x) { p1[e] = 0.f; p2[e] = 0.f; }
  for (int e = t; e < NWG * 32; e += blockDim.x) g_flag[e] = 0u;
}

__device__ __forceinline__ float sigm(float x) { return 1.f / (1.f + expf(-x)); }

__global__ __launch_bounds__(NTHR, 2) void lstm_main(
    const float* __restrict__ x_seq,
    const float* __restrict__ W_ih1, const float* __restrict__ W_hh1,
    const float* __restrict__ b_ih1, const float* __restrict__ b_hh1,
    const float* __restrict__ W_ih2, const float* __restrict__ W_hh2,
    const float* __restrict__ b_ih2, const float* __restrict__ b_hh2,
    const float* __restrict__ W_out, const float* __restrict__ b_out,
    float* __restrict__ out)
{
  const int wg   = blockIdx.x;
  const int tid  = threadIdx.x;
  const int wave = tid >> 6;     // 0..7
  const int lane = tid & 63;
  const int g    = lane >> 4;    // gate 0..3 (i,f,g,o)
  const int s    = lane & 15;    // strip 0..15
  const int j    = wg * 8 + wave;      // owned hidden index (both layers)
  const int r    = g * HDIM + j;       // gate row in [0,2048)

  // ---- weights -> VGPRs (held for the whole kernel) ----
  // layer1 row = [W_hh1[r,0:512] | W_ih1[r,0:64]]; thread covers e = s*36 .. s*36+35
  float wa[36];
#pragma unroll
  for (int m = 0; m < 36; ++m) {
    int e = s * 36 + m;
    wa[m] = (e < HDIM) ? W_hh1[(size_t)r * HDIM + e]
                       : W_ih1[(size_t)r * IDIM + (e - HDIM)];
  }
  // layer2 row = [W_ih2[r,0:512] | W_hh2[r,0:512]]; thread covers e = s*64 .. s*64+63,
  // chunk-rotated by s to avoid LDS bank conflicts on the stride-256B read pattern.
  float wb[64];
#pragma unroll
  for (int c = 0; c < 16; ++c) {
#pragma unroll
    for (int i = 0; i < 4; ++i) {
      int er = s * 64 + ((c + s) & 15) * 4 + i;   // 0..1023
      wb[c * 4 + i] = (er < HDIM) ? W_ih2[(size_t)r * HDIM + er]
                                  : W_hh2[(size_t)r * HDIM + (er - HDIM)];
    }
  }
  const float bi1 = b_ih1[j] + b_hh1[j];
  const float bf1 = b_ih1[HDIM + j] + b_hh1[HDIM + j];
  const float bg1 = b_ih1[2 * HDIM + j] + b_hh1[2 * HDIM + j];
  const float bo1 = b_ih1[3 * HDIM + j] + b_hh1[3 * HDIM + j];
  const float bi2 = b_ih2[j] + b_hh2[j];
  const float bf2 = b_ih2[HDIM + j] + b_hh2[HDIM + j];
  const float bg2 = b_ih2[2 * HDIM + j] + b_hh2[2 * HDIM + j];
  const float bo2 = b_ih2[3 * HDIM + j] + b_hh2[3 * HDIM + j];

  float c1 = 0.f, c2 = 0.f;

  __shared__ __align__(16) float vec[HDIM + IDIM + HDIM]; // [h1_prev | x_k | h2_prev]

  for (int k = 0; k <= T_LEN; ++k) {
    // ---- cooperative LDS fill ----
    for (int e = tid; e < HDIM + IDIM + HDIM; e += NTHR) {
      float v;
      if (e < HDIM)
        v = __hip_atomic_load(&g_h1[(k + 1) & 1][e], __ATOMIC_RELAXED, __HIP_MEMORY_SCOPE_AGENT);
      else if (e < HDIM + IDIM)
        v = (k < T_LEN) ? x_seq[(size_t)k * IDIM + (e - HDIM)] : 0.f;
      else
        v = __hip_atomic_load(&g_h2[k & 1][e - (HDIM + IDIM)], __ATOMIC_RELAXED, __HIP_MEMORY_SCOPE_AGENT);
      vec[e] = v;
    }
    __syncthreads();

    // ---- layer 1, step k ----
    if (k < T_LEN) {
      float acc = 0.f;
#pragma unroll
      for (int mc = 0; mc < 9; ++mc) {
        const float4 hv = *reinterpret_cast<const float4*>(&vec[s * 36 + mc * 4]);
        acc = fmaf(wa[mc * 4 + 0], hv.x, acc);
        acc = fmaf(wa[mc * 4 + 1], hv.y, acc);
        acc = fmaf(wa[mc * 4 + 2], hv.z, acc);
        acc = fmaf(wa[mc * 4 + 3], hv.w, acc);
      }
      acc += __shfl_xor(acc, 8, 16);
      acc += __shfl_xor(acc, 4, 16);
      acc += __shfl_xor(acc, 2, 16);
      acc += __shfl_xor(acc, 1, 16);
      const float si = __shfl(acc, 0, 64) + bi1;
      const float sf = __shfl(acc, 16, 64) + bf1;
      const float sg = __shfl(acc, 32, 64) + bg1;
      const float so = __shfl(acc, 48, 64) + bo1;
      c1 = sigm(sf) * c1 + sigm(si) * tanhf(sg);
      const float h1v = sigm(so) * tanhf(c1);
      if (lane == 0)
        __hip_atomic_store(&g_h1[k & 1][j], h1v, __ATOMIC_RELAXED, __HIP_MEMORY_SCOPE_AGENT);
    }

    // ---- layer 2, step k-1 (pipelined) ----
    if (k > 0) {
      const int vb = (s < 8) ? 0 : IDIM;  // skip the x-gap for the h2 half
      float acc = 0.f;
#pragma unroll
      for (int c = 0; c < 16; ++c) {
        const int off = s * 64 + ((c + s) & 15) * 4 + vb;
        const float4 hv = *reinterpret_cast<const float4*>(&vec[off]);
        acc = fmaf(wb[c * 4 + 0], hv.x, acc);
        acc = fmaf(wb[c * 4 + 1], hv.y, acc);
        acc = fmaf(wb[c * 4 + 2], hv.z, acc);
        acc = fmaf(wb[c * 4 + 3], hv.w, acc);
      }
      acc += __shfl_xor(acc, 8, 16);
      acc += __shfl_xor(acc, 4, 16);
      acc += __shfl_xor(acc, 2, 16);
      acc += __shfl_xor(acc, 1, 16);
      const float si = __shfl(acc, 0, 64) + bi2;
      const float sf = __shfl(acc, 16, 64) + bf2;
      const float sg = __shfl(acc, 32, 64) + bg2;
      const float so = __shfl(acc, 48, 64) + bo2;
      c2 = sigm(sf) * c2 + sigm(si) * tanhf(sg);
      const float h2v = sigm(so) * tanhf(c2);
      if (lane == 0)
        __hip_atomic_store(&g_h2[(k + 1) & 1][j], h2v, __ATOMIC_RELAXED, __HIP_MEMORY_SCOPE_AGENT);
    }

    // ---- device-wide barrier: distributed flag array, monotonic ----
    __syncthreads();   // all h stores issued, all LDS reads done
    if (tid == 0)
      __hip_atomic_store(&g_flag[wg * 32], (unsigned)(k + 1),
                         __ATOMIC_RELEASE, __HIP_MEMORY_SCOPE_AGENT);
    for (;;) {
      unsigned v = 0xFFFFFFFFu;
      if (tid < NWG)
        v = __hip_atomic_load(&g_flag[tid * 32], __ATOMIC_RELAXED, __HIP_MEMORY_SCOPE_AGENT);
      if (__syncthreads_and((int)(v > (unsigned)k))) break;
      __builtin_amdgcn_s_sleep(1);
    }
    __threadfence();   // acquire: make other XCDs' h stores visible
  }

  // ---- final output: out = W_out . h2_final + b_out (single scalar) ----
  if (wg == 0 && wave == 0) {
    const int fin = (T_LEN + 1) & 1;
    float acc = 0.f;
#pragma unroll
    for (int e = 0; e < HDIM / 64; ++e) {
      const int idx = lane + e * 64;
      const float h = __hip_atomic_load(&g_h2[fin][idx], __ATOMIC_RELAXED, __HIP_MEMORY_SCOPE_AGENT);
      acc = fmaf(W_out[idx], h, acc);
    }
    acc += __shfl_xor(acc, 32, 64);
    acc += __shfl_xor(acc, 16, 64);
    acc += __shfl_xor(acc, 8, 64);
    acc += __shfl_xor(acc, 4, 64);
    acc += __shfl_xor(acc, 2, 64);
    acc += __shfl_xor(acc, 1, 64);
    if (lane == 0) out[0] = acc + b_out[0];
  }
}

extern "C" void kernel_launch(void* const* d_in, const int* in_sizes, int n_in,
                              void* d_out, int out_size, void* d_ws, size_t ws_size,
                              hipStream_t stream) {
  const float* x_seq = (const float*)d_in[0];
  const float* W_ih1 = (const float*)d_in[1];
  const float* W_hh1 = (const float*)d_in[2];
  const float* b_ih1 = (const float*)d_in[3];
  const float* b_hh1 = (const float*)d_in[4];
  const float* W_ih2 = (const float*)d_in[5];
  const float* W_hh2 = (const float*)d_in[6];
  const float* b_ih2 = (const float*)d_in[7];
  const float* b_hh2 = (const float*)d_in[8];
  const float* W_out = (const float*)d_in[9];
  const float* b_out = (const float*)d_in[10];
  float* out = (float*)d_out;

  hipLaunchKernelGGL(lstm_init, dim3(1), dim3(256), 0, stream);
  hipLaunchKernelGGL(lstm_main, dim3(NWG), dim3(NTHR), 0, stream,
                     x_seq, W_ih1, W_hh1, b_ih1, b_hh1,
                     W_ih2, W_hh2, b_ih2, b_hh2, W_out, b_out, out);
}

// Round 3
// 281757.373 us; speedup vs baseline: 2.6476x; 2.6476x over previous
//
#include <hip/hip_runtime.h>

#define IDIM  64
#define HDIM  512
#define T_LEN 65536
#define NWG   64
#define NTHR  512

// Tagged hidden state: high 32 bits = tick tag, low 32 bits = float payload.
// The tag check doubles as the device-wide barrier (data+signal in one 8B word).
__device__ unsigned long long g_h1[2][HDIM];
__device__ unsigned long long g_h2[2][HDIM];

__device__ __forceinline__ unsigned long long pack(float v, int k) {
  return ((unsigned long long)(unsigned)k << 32) | (unsigned long long)__float_as_uint(v);
}

__global__ void lstm_init() {
  int t = threadIdx.x;
  for (int e = t; e < HDIM; e += blockDim.x) {
    g_h1[0][e] = 0xFFFFFFFF00000000ull;  // tag=-1, val=0
    g_h1[1][e] = 0xFFFFFFFF00000000ull;  // read at tick 0 (expect -1)
    g_h2[0][e] = 0xFFFFFFFF00000000ull;  // read at tick 0 (expect -1)
    g_h2[1][e] = 0x0000000000000000ull;  // tag=0,val=0: read at tick 1 (expect 0) -- h2(-1)
  }
}

__device__ __forceinline__ float sigm(float x) { return 1.f / (1.f + expf(-x)); }

__global__ __launch_bounds__(NTHR, 1) void lstm_main(
    const float* __restrict__ x_seq,
    const float* __restrict__ W_ih1, const float* __restrict__ W_hh1,
    const float* __restrict__ b_ih1, const float* __restrict__ b_hh1,
    const float* __restrict__ W_ih2, const float* __restrict__ W_hh2,
    const float* __restrict__ b_ih2, const float* __restrict__ b_hh2,
    const float* __restrict__ W_out, const float* __restrict__ b_out,
    float* __restrict__ out)
{
  const int wg   = blockIdx.x;
  const int tid  = threadIdx.x;
  const int wave = tid >> 6;     // 0..7
  const int lane = tid & 63;
  const int g    = lane >> 4;    // gate 0..3 (i,f,g,o)
  const int s    = lane & 15;    // strip 0..15
  const int j    = wg * 8 + wave;      // owned hidden index (both layers)
  const int r    = g * HDIM + j;       // gate row in [0,2048)

  // ---- weights -> VGPRs (held for the whole kernel) ----
  // layer1 row = [W_hh1[r,0:512] | W_ih1[r,0:64]]; thread covers e = s*36 .. s*36+35
  float wa[36];
#pragma unroll
  for (int m = 0; m < 36; ++m) {
    int e = s * 36 + m;
    wa[m] = (e < HDIM) ? W_hh1[(size_t)r * HDIM + e]
                       : W_ih1[(size_t)r * IDIM + (e - HDIM)];
  }
  // layer2 row = [W_ih2[r,0:512] | W_hh2[r,0:512]]; thread covers e = s*64 .. s*64+63,
  // chunk-rotated by s to avoid LDS bank conflicts on the stride-256B read pattern.
  float wb[64];
#pragma unroll
  for (int c = 0; c < 16; ++c) {
#pragma unroll
    for (int i = 0; i < 4; ++i) {
      int er = s * 64 + ((c + s) & 15) * 4 + i;   // 0..1023
      wb[c * 4 + i] = (er < HDIM) ? W_ih2[(size_t)r * HDIM + er]
                                  : W_hh2[(size_t)r * HDIM + (er - HDIM)];
    }
  }
  const float bi1 = b_ih1[j] + b_hh1[j];
  const float bf1 = b_ih1[HDIM + j] + b_hh1[HDIM + j];
  const float bg1 = b_ih1[2 * HDIM + j] + b_hh1[2 * HDIM + j];
  const float bo1 = b_ih1[3 * HDIM + j] + b_hh1[3 * HDIM + j];
  const float bi2 = b_ih2[j] + b_hh2[j];
  const float bf2 = b_ih2[HDIM + j] + b_hh2[HDIM + j];
  const float bg2 = b_ih2[2 * HDIM + j] + b_hh2[2 * HDIM + j];
  const float bo2 = b_ih2[3 * HDIM + j] + b_hh2[3 * HDIM + j];

  float c1 = 0.f, c2 = 0.f;
  int budget = 1 << 23;   // safety: terminate (wrong) instead of hanging if protocol breaks

  __shared__ __align__(16) float vec[HDIM + IDIM + HDIM]; // [h1_prev | x_k | h2_prev]

  for (int k = 0; k <= T_LEN; ++k) {
    const unsigned expect = (unsigned)(k - 1);
    const int p1 = (k + 1) & 1;   // h1(k-1) lives here (tag k-1)
    const int p2 = k & 1;         // h2(k-2) lives here (tag k-1)

    // x load issued before the poll so its latency hides under it
    float xv = 0.f;
    if (tid < IDIM && k < T_LEN) xv = x_seq[(size_t)k * IDIM + tid];

    // ---- fused poll+load: wait until this thread's two h-slots carry tag k-1 ----
    unsigned long long a, b;
    for (;;) {
      a = __hip_atomic_load(&g_h1[p1][tid], __ATOMIC_RELAXED, __HIP_MEMORY_SCOPE_AGENT);
      b = __hip_atomic_load(&g_h2[p2][tid], __ATOMIC_RELAXED, __HIP_MEMORY_SCOPE_AGENT);
      int ok = ((unsigned)(a >> 32) == expect) & ((unsigned)(b >> 32) == expect);
      if (__syncthreads_and(ok)) break;
      if (--budget <= 0) break;   // uniform across block: same iteration count everywhere
    }
    vec[tid] = __uint_as_float((unsigned)a);
    vec[HDIM + IDIM + tid] = __uint_as_float((unsigned)b);
    if (tid < IDIM) vec[HDIM + tid] = xv;
    __syncthreads();

    // ---- layer 1, step k ----
    if (k < T_LEN) {
      float acc = 0.f;
#pragma unroll
      for (int mc = 0; mc < 9; ++mc) {
        const float4 hv = *reinterpret_cast<const float4*>(&vec[s * 36 + mc * 4]);
        acc = fmaf(wa[mc * 4 + 0], hv.x, acc);
        acc = fmaf(wa[mc * 4 + 1], hv.y, acc);
        acc = fmaf(wa[mc * 4 + 2], hv.z, acc);
        acc = fmaf(wa[mc * 4 + 3], hv.w, acc);
      }
      acc += __shfl_xor(acc, 8, 16);
      acc += __shfl_xor(acc, 4, 16);
      acc += __shfl_xor(acc, 2, 16);
      acc += __shfl_xor(acc, 1, 16);
      const float si = __shfl(acc, 0, 64) + bi1;
      const float sf = __shfl(acc, 16, 64) + bf1;
      const float sg = __shfl(acc, 32, 64) + bg1;
      const float so = __shfl(acc, 48, 64) + bo1;
      c1 = sigm(sf) * c1 + sigm(si) * tanhf(sg);
      const float h1v = sigm(so) * tanhf(c1);
      if (lane == 0)
        __hip_atomic_store(&g_h1[k & 1][j], pack(h1v, k),
                           __ATOMIC_RELAXED, __HIP_MEMORY_SCOPE_AGENT);
    }

    // ---- layer 2, step k-1 (pipelined) ----
    if (k > 0) {
      const int vb = (s < 8) ? 0 : IDIM;  // skip the x-gap for the h2 half
      float acc = 0.f;
#pragma unroll
      for (int c = 0; c < 16; ++c) {
        const int off = s * 64 + ((c + s) & 15) * 4 + vb;
        const float4 hv = *reinterpret_cast<const float4*>(&vec[off]);
        acc = fmaf(wb[c * 4 + 0], hv.x, acc);
        acc = fmaf(wb[c * 4 + 1], hv.y, acc);
        acc = fmaf(wb[c * 4 + 2], hv.z, acc);
        acc = fmaf(wb[c * 4 + 3], hv.w, acc);
      }
      acc += __shfl_xor(acc, 8, 16);
      acc += __shfl_xor(acc, 4, 16);
      acc += __shfl_xor(acc, 2, 16);
      acc += __shfl_xor(acc, 1, 16);
      const float si = __shfl(acc, 0, 64) + bi2;
      const float sf = __shfl(acc, 16, 64) + bf2;
      const float sg = __shfl(acc, 32, 64) + bg2;
      const float so = __shfl(acc, 48, 64) + bo2;
      c2 = sigm(sf) * c2 + sigm(si) * tanhf(sg);
      const float h2v = sigm(so) * tanhf(c2);
      if (lane == 0)
        __hip_atomic_store(&g_h2[(k + 1) & 1][j], pack(h2v, k),
                           __ATOMIC_RELAXED, __HIP_MEMORY_SCOPE_AGENT);
    }
    // no trailing barrier: the next tick's poll-sync separates LDS reuse
  }

  // ---- final output: out = W_out . h2(T-1) + b_out ----
  if (wg == 0 && wave == 0) {
    float acc = 0.f;
#pragma unroll
    for (int e = 0; e < HDIM / 64; ++e) {
      const int idx = lane + e * 64;
      unsigned long long u;
      int bud = 1 << 23;
      do {
        u = __hip_atomic_load(&g_h2[1][idx], __ATOMIC_RELAXED, __HIP_MEMORY_SCOPE_AGENT);
      } while ((unsigned)(u >> 32) != (unsigned)T_LEN && --bud > 0);
      acc = fmaf(W_out[idx], __uint_as_float((unsigned)u), acc);
    }
    acc += __shfl_xor(acc, 32, 64);
    acc += __shfl_xor(acc, 16, 64);
    acc += __shfl_xor(acc, 8, 64);
    acc += __shfl_xor(acc, 4, 64);
    acc += __shfl_xor(acc, 2, 64);
    acc += __shfl_xor(acc, 1, 64);
    if (lane == 0) out[0] = acc + b_out[0];
  }
}

extern "C" void kernel_launch(void* const* d_in, const int* in_sizes, int n_in,
                              void* d_out, int out_size, void* d_ws, size_t ws_size,
                              hipStream_t stream) {
  const float* x_seq = (const float*)d_in[0];
  const float* W_ih1 = (const float*)d_in[1];
  const float* W_hh1 = (const float*)d_in[2];
  const float* b_ih1 = (const float*)d_in[3];
  const float* b_hh1 = (const float*)d_in[4];
  const float* W_ih2 = (const float*)d_in[5];
  const float* W_hh2 = (const float*)d_in[6];
  const float* b_ih2 = (const float*)d_in[7];
  const float* b_hh2 = (const float*)d_in[8];
  const float* W_out = (const float*)d_in[9];
  const float* b_out = (const float*)d_in[10];
  float* out = (float*)d_out;

  hipLaunchKernelGGL(lstm_init, dim3(1), dim3(256), 0, stream);
  hipLaunchKernelGGL(lstm_main, dim3(NWG), dim3(NTHR), 0, stream,
                     x_seq, W_ih1, W_hh1, b_ih1, b_hh1,
                     W_ih2, W_hh2, b_ih2, b_hh2, W_out, b_out, out);
}

// Round 4
// 164643.311 us; speedup vs baseline: 4.5308x; 1.7113x over previous
//
#include <hip/hip_runtime.h>

#define IDIM  64
#define HDIM  512
#define T_LEN 65536
#define NWG   64
#define NTHR  512

// Tagged hidden state: high 32 bits = tick tag, low 32 bits = float payload.
// The tag check doubles as the device-wide barrier (data+signal in one 8B word).
__device__ unsigned long long g_h1[2][HDIM];
__device__ unsigned long long g_h2[2][HDIM];

__device__ __forceinline__ unsigned long long pack(float v, int k) {
  return ((unsigned long long)(unsigned)k << 32) | (unsigned long long)__float_as_uint(v);
}

__global__ void lstm_init() {
  int t = threadIdx.x;
  for (int e = t; e < HDIM; e += blockDim.x) {
    g_h1[0][e] = 0xFFFFFFFF00000000ull;  // tag=-1, val=0
    g_h1[1][e] = 0xFFFFFFFF00000000ull;  // read at tick 0 (expect -1)
    g_h2[0][e] = 0xFFFFFFFF00000000ull;  // read at tick 0 (expect -1)
    g_h2[1][e] = 0x0000000000000000ull;  // tag=0,val=0: read at tick 1 (expect 0) -- h2(-1)
  }
}

__device__ __forceinline__ float sigm(float x) { return 1.f / (1.f + expf(-x)); }

__global__ __launch_bounds__(NTHR)
__attribute__((amdgpu_waves_per_eu(2, 2)))   // pin 2 waves/EU -> 256-VGPR budget: keep weights registerized
void lstm_main(
    const float* __restrict__ x_seq,
    const float* __restrict__ W_ih1, const float* __restrict__ W_hh1,
    const float* __restrict__ b_ih1, const float* __restrict__ b_hh1,
    const float* __restrict__ W_ih2, const float* __restrict__ W_hh2,
    const float* __restrict__ b_ih2, const float* __restrict__ b_hh2,
    const float* __restrict__ W_out, const float* __restrict__ b_out,
    float* __restrict__ out)
{
  const int wg   = blockIdx.x;
  const int tid  = threadIdx.x;
  const int wave = tid >> 6;     // 0..7
  const int lane = tid & 63;
  const int g    = lane >> 4;    // gate 0..3 (i,f,g,o)
  const int s    = lane & 15;    // strip 0..15
  const int j    = wg * 8 + wave;      // owned hidden index (both layers)
  const int r    = g * HDIM + j;       // gate row in [0,2048)

  // ---- weights -> VGPRs (held for the whole kernel) ----
  // layer1 row = [W_hh1[r,0:512] | W_ih1[r,0:64]]; thread covers e = s*36 .. s*36+35
  float wa[36];
#pragma unroll
  for (int m = 0; m < 36; ++m) {
    int e = s * 36 + m;
    wa[m] = (e < HDIM) ? W_hh1[(size_t)r * HDIM + e]
                       : W_ih1[(size_t)r * IDIM + (e - HDIM)];
  }
  // layer2 row = [W_ih2[r,0:512] | W_hh2[r,0:512]]; thread covers e = s*64 .. s*64+63,
  // chunk-rotated by s to avoid LDS bank conflicts on the stride-256B read pattern.
  float wb[64];
#pragma unroll
  for (int c = 0; c < 16; ++c) {
#pragma unroll
    for (int i = 0; i < 4; ++i) {
      int er = s * 64 + ((c + s) & 15) * 4 + i;   // 0..1023
      wb[c * 4 + i] = (er < HDIM) ? W_ih2[(size_t)r * HDIM + er]
                                  : W_hh2[(size_t)r * HDIM + (er - HDIM)];
    }
  }
  const float bi1 = b_ih1[j] + b_hh1[j];
  const float bf1 = b_ih1[HDIM + j] + b_hh1[HDIM + j];
  const float bg1 = b_ih1[2 * HDIM + j] + b_hh1[2 * HDIM + j];
  const float bo1 = b_ih1[3 * HDIM + j] + b_hh1[3 * HDIM + j];
  const float bi2 = b_ih2[j] + b_hh2[j];
  const float bf2 = b_ih2[HDIM + j] + b_hh2[HDIM + j];
  const float bg2 = b_ih2[2 * HDIM + j] + b_hh2[2 * HDIM + j];
  const float bo2 = b_ih2[3 * HDIM + j] + b_hh2[3 * HDIM + j];

  float c1 = 0.f, c2 = 0.f;

  __shared__ __align__(16) float vec[HDIM + IDIM + HDIM]; // [h1_prev | x_k | h2_prev]

  for (int k = 0; k <= T_LEN; ++k) {
    const unsigned expect = (unsigned)(k - 1);
    const int p1 = (k + 1) & 1;   // h1(k-1) lives here (tag k-1)
    const int p2 = k & 1;         // h2(k-2) lives here (tag k-1)

    // x load issued before the poll so its latency hides under it
    float xv = 0.f;
    if (tid < IDIM && k < T_LEN) xv = x_seq[(size_t)k * IDIM + tid];

    // ---- per-thread spin on this thread's two slots (no block barrier in loop) ----
    unsigned long long a = 0, b = 0;
    bool ok1 = false, ok2 = false;
    int bud = 1 << 22;   // safety: terminate (wrong) instead of hanging if protocol breaks
    do {
      if (!ok1) {
        a = __hip_atomic_load(&g_h1[p1][tid], __ATOMIC_RELAXED, __HIP_MEMORY_SCOPE_AGENT);
        ok1 = ((unsigned)(a >> 32) == expect);
      }
      if (!ok2) {
        b = __hip_atomic_load(&g_h2[p2][tid], __ATOMIC_RELAXED, __HIP_MEMORY_SCOPE_AGENT);
        ok2 = ((unsigned)(b >> 32) == expect);
      }
    } while ((!ok1 || !ok2) && --bud > 0);

    vec[tid] = __uint_as_float((unsigned)a);
    vec[HDIM + IDIM + tid] = __uint_as_float((unsigned)b);
    if (tid < IDIM) vec[HDIM + tid] = xv;
    __syncthreads();   // barrier1: fills complete (also: all payload reads captured -> safe to publish)

    // ---- layer 1, step k ----
    if (k < T_LEN) {
      float acc = 0.f;
#pragma unroll
      for (int mc = 0; mc < 9; ++mc) {
        const float4 hv = *reinterpret_cast<const float4*>(&vec[s * 36 + mc * 4]);
        acc = fmaf(wa[mc * 4 + 0], hv.x, acc);
        acc = fmaf(wa[mc * 4 + 1], hv.y, acc);
        acc = fmaf(wa[mc * 4 + 2], hv.z, acc);
        acc = fmaf(wa[mc * 4 + 3], hv.w, acc);
      }
      acc += __shfl_xor(acc, 8, 16);
      acc += __shfl_xor(acc, 4, 16);
      acc += __shfl_xor(acc, 2, 16);
      acc += __shfl_xor(acc, 1, 16);
      const float si = __shfl(acc, 0, 64) + bi1;
      const float sf = __shfl(acc, 16, 64) + bf1;
      const float sg = __shfl(acc, 32, 64) + bg1;
      const float so = __shfl(acc, 48, 64) + bo1;
      c1 = sigm(sf) * c1 + sigm(si) * tanhf(sg);
      const float h1v = sigm(so) * tanhf(c1);
      if (lane == 0)
        __hip_atomic_store(&g_h1[k & 1][j], pack(h1v, k),
                           __ATOMIC_RELAXED, __HIP_MEMORY_SCOPE_AGENT);
    }

    // ---- layer 2, step k-1 (pipelined) ----
    if (k > 0) {
      const int vb = (s < 8) ? 0 : IDIM;  // skip the x-gap for the h2 half
      float acc = 0.f;
#pragma unroll
      for (int c = 0; c < 16; ++c) {
        const int off = s * 64 + ((c + s) & 15) * 4 + vb;
        const float4 hv = *reinterpret_cast<const float4*>(&vec[off]);
        acc = fmaf(wb[c * 4 + 0], hv.x, acc);
        acc = fmaf(wb[c * 4 + 1], hv.y, acc);
        acc = fmaf(wb[c * 4 + 2], hv.z, acc);
        acc = fmaf(wb[c * 4 + 3], hv.w, acc);
      }
      acc += __shfl_xor(acc, 8, 16);
      acc += __shfl_xor(acc, 4, 16);
      acc += __shfl_xor(acc, 2, 16);
      acc += __shfl_xor(acc, 1, 16);
      const float si = __shfl(acc, 0, 64) + bi2;
      const float sf = __shfl(acc, 16, 64) + bf2;
      const float sg = __shfl(acc, 32, 64) + bg2;
      const float so = __shfl(acc, 48, 64) + bo2;
      c2 = sigm(sf) * c2 + sigm(si) * tanhf(sg);
      const float h2v = sigm(so) * tanhf(c2);
      if (lane == 0)
        __hip_atomic_store(&g_h2[(k + 1) & 1][j], pack(h2v, k),
                           __ATOMIC_RELAXED, __HIP_MEMORY_SCOPE_AGENT);
    }

    __syncthreads();   // barrier2: all LDS reads of tick k done before tick k+1 overwrites vec
  }

  // ---- final output: out = W_out . h2(T-1) + b_out ----
  if (wg == 0 && wave == 0) {
    float acc = 0.f;
#pragma unroll
    for (int e = 0; e < HDIM / 64; ++e) {
      const int idx = lane + e * 64;
      unsigned long long u;
      int bud = 1 << 22;
      do {
        u = __hip_atomic_load(&g_h2[1][idx], __ATOMIC_RELAXED, __HIP_MEMORY_SCOPE_AGENT);
      } while ((unsigned)(u >> 32) != (unsigned)T_LEN && --bud > 0);
      acc = fmaf(W_out[idx], __uint_as_float((unsigned)u), acc);
    }
    acc += __shfl_xor(acc, 32, 64);
    acc += __shfl_xor(acc, 16, 64);
    acc += __shfl_xor(acc, 8, 64);
    acc += __shfl_xor(acc, 4, 64);
    acc += __shfl_xor(acc, 2, 64);
    acc += __shfl_xor(acc, 1, 64);
    if (lane == 0) out[0] = acc + b_out[0];
  }
}

extern "C" void kernel_launch(void* const* d_in, const int* in_sizes, int n_in,
                              void* d_out, int out_size, void* d_ws, size_t ws_size,
                              hipStream_t stream) {
  const float* x_seq = (const float*)d_in[0];
  const float* W_ih1 = (const float*)d_in[1];
  const float* W_hh1 = (const float*)d_in[2];
  const float* b_ih1 = (const float*)d_in[3];
  const float* b_hh1 = (const float*)d_in[4];
  const float* W_ih2 = (const float*)d_in[5];
  const float* W_hh2 = (const float*)d_in[6];
  const float* b_ih2 = (const float*)d_in[7];
  const float* b_hh2 = (const float*)d_in[8];
  const float* W_out = (const float*)d_in[9];
  const float* b_out = (const float*)d_in[10];
  float* out = (float*)d_out;

  hipLaunchKernelGGL(lstm_init, dim3(1), dim3(256), 0, stream);
  hipLaunchKernelGGL(lstm_main, dim3(NWG), dim3(NTHR), 0, stream,
                     x_seq, W_ih1, W_hh1, b_ih1, b_hh1,
                     W_ih2, W_hh2, b_ih2, b_hh2, W_out, b_out, out);
}

// Round 5
// 129331.299 us; speedup vs baseline: 5.7679x; 1.2730x over previous
//
#include <hip/hip_runtime.h>

#define IDIM  64
#define HDIM  512
#define T_LEN 65536
#define NWG   128
#define NTHR  512

// Tagged hidden state: high 32 bits = tick tag, low 32 bits = float payload.
// The tag check doubles as the device-wide barrier (data+signal in one 8B word).
__device__ unsigned long long g_h1[2][HDIM];
__device__ unsigned long long g_h2[2][HDIM];

__device__ __forceinline__ unsigned long long pack(float v, int k) {
  return ((unsigned long long)(unsigned)k << 32) | (unsigned long long)__float_as_uint(v);
}

__global__ void lstm_init() {
  int t = threadIdx.x;
  for (int e = t; e < HDIM; e += blockDim.x) {
    g_h1[0][e] = 0xFFFFFFFF00000000ull;  // tag=-1, val=0
    g_h1[1][e] = 0xFFFFFFFF00000000ull;  // read at tick 0 (expect -1)
    g_h2[0][e] = 0xFFFFFFFF00000000ull;  // read at tick 0 (expect -1)
    g_h2[1][e] = 0x0000000000000000ull;  // tag=0,val=0: h2(-1), read at tick 1
  }
}

__global__ __launch_bounds__(NTHR)
__attribute__((amdgpu_waves_per_eu(2, 2)))   // 2 waves/EU -> 256-VGPR budget
void lstm_main(
    const float* __restrict__ x_seq,
    const float* __restrict__ W_ih1, const float* __restrict__ W_hh1,
    const float* __restrict__ b_ih1, const float* __restrict__ b_hh1,
    const float* __restrict__ W_ih2, const float* __restrict__ W_hh2,
    const float* __restrict__ b_ih2, const float* __restrict__ b_hh2,
    const float* __restrict__ W_out, const float* __restrict__ b_out,
    float* __restrict__ out)
{
  const int wg   = blockIdx.x;
  const int tid  = threadIdx.x;
  const int wave = tid >> 6;      // 0..7
  const int role = wave >> 2;     // 0 = layer1, 1 = layer2
  const int lane = tid & 63;
  const int g    = lane >> 4;     // gate 0..3 (i,f,g,o)
  const int s    = lane & 15;     // strip 0..15
  const int j    = wg * 4 + (wave & 3);   // owned hidden index for this (j,layer) wave
  const int r    = g * HDIM + j;          // gate row in [0,2048)

  // ---- weights -> VGPRs: ONE array, role-dependent contents (max 64 live floats) ----
  float w[64];
  if (role == 0) {
    // layer1 row = [W_hh1[r,0:512] | W_ih1[r,0:64]]; lane covers e = s*36 .. s*36+35
#pragma unroll
    for (int m = 0; m < 36; ++m) {
      int e = s * 36 + m;
      w[m] = (e < HDIM) ? W_hh1[(size_t)r * HDIM + e]
                        : W_ih1[(size_t)r * IDIM + (e - HDIM)];
    }
#pragma unroll
    for (int m = 0; m < 36; ++m) asm volatile("" : "+v"(w[m]));  // forbid remat
  } else {
    // layer2 row = [W_ih2[r,0:512] | W_hh2[r,0:512]]; lane covers e = s*64 .. s*64+63,
    // chunk-rotated by s to avoid LDS bank conflicts on the stride-256B read pattern.
#pragma unroll
    for (int c = 0; c < 16; ++c) {
#pragma unroll
      for (int i = 0; i < 4; ++i) {
        int er = s * 64 + ((c + s) & 15) * 4 + i;   // 0..1023
        w[c * 4 + i] = (er < HDIM) ? W_ih2[(size_t)r * HDIM + er]
                                   : W_hh2[(size_t)r * HDIM + (er - HDIM)];
      }
    }
#pragma unroll
    for (int m = 0; m < 64; ++m) asm volatile("" : "+v"(w[m]));  // forbid remat
  }
  // single per-thread bias: gate g of row j for this layer
  const float bsel = (role == 0) ? (b_ih1[r] + b_hh1[r]) : (b_ih2[r] + b_hh2[r]);

  float cst = 0.f;                 // cell state for owned (j, layer)
  int bud = 1 << 24;               // GLOBAL spin budget: fail fast, not per-tick

  __shared__ __align__(16) float vec[2][HDIM + IDIM + HDIM]; // [h1_prev | x_k | h2_prev] x2

  for (int k = 0; k <= T_LEN; ++k) {
    const unsigned expect = (unsigned)(k - 1);
    const int p1  = (k + 1) & 1;  // h1(k-1) lives here (tag k-1)
    const int p2  = k & 1;        // h2(k-2) lives here (tag k-1)
    const int buf = k & 1;

    // x load issued before the poll so its latency hides under it
    float xv = 0.f;
    if (tid < IDIM && k < T_LEN) xv = x_seq[(size_t)k * IDIM + tid];

    // ---- per-thread spin on this thread's two slots (no block barrier in loop) ----
    unsigned long long a = 0, b = 0;
    bool ok1 = false, ok2 = false;
    do {
      if (!ok1) {
        a = __hip_atomic_load(&g_h1[p1][tid], __ATOMIC_RELAXED, __HIP_MEMORY_SCOPE_AGENT);
        ok1 = ((unsigned)(a >> 32) == expect);
      }
      if (!ok2) {
        b = __hip_atomic_load(&g_h2[p2][tid], __ATOMIC_RELAXED, __HIP_MEMORY_SCOPE_AGENT);
        ok2 = ((unsigned)(b >> 32) == expect);
      }
    } while ((!ok1 || !ok2) && --bud > 0);

    vec[buf][tid] = __uint_as_float((unsigned)a);
    vec[buf][HDIM + IDIM + tid] = __uint_as_float((unsigned)b);
    if (tid < IDIM) vec[buf][HDIM + tid] = xv;
    __syncthreads();   // barrier1 (only barrier per tick; vec is double-buffered)

    // ---- compute: role 0 = layer1 step k; role 1 = layer2 step k-1 ----
    const bool active = (role == 0) ? (k < T_LEN) : (k > 0);
    if (active) {
      float acc = 0.f;
      if (role == 0) {
#pragma unroll
        for (int mc = 0; mc < 9; ++mc) {
          const float4 hv = *reinterpret_cast<const float4*>(&vec[buf][s * 36 + mc * 4]);
          acc = fmaf(w[mc * 4 + 0], hv.x, acc);
          acc = fmaf(w[mc * 4 + 1], hv.y, acc);
          acc = fmaf(w[mc * 4 + 2], hv.z, acc);
          acc = fmaf(w[mc * 4 + 3], hv.w, acc);
        }
      } else {
        const int vb = (s < 8) ? 0 : IDIM;  // skip the x-gap for the h2 half
#pragma unroll
        for (int c = 0; c < 16; ++c) {
          const int off = s * 64 + ((c + s) & 15) * 4 + vb;
          const float4 hv = *reinterpret_cast<const float4*>(&vec[buf][off]);
          acc = fmaf(w[c * 4 + 0], hv.x, acc);
          acc = fmaf(w[c * 4 + 1], hv.y, acc);
          acc = fmaf(w[c * 4 + 2], hv.z, acc);
          acc = fmaf(w[c * 4 + 3], hv.w, acc);
        }
      }
      acc += __shfl_xor(acc, 8, 16);
      acc += __shfl_xor(acc, 4, 16);
      acc += __shfl_xor(acc, 2, 16);
      acc += __shfl_xor(acc, 1, 16);

      // per-group activation: group g activates ITS gate, then broadcast activated values.
      // tanh(x) = 2*sigmoid(2x) - 1 (exact identity) -> single sigmoid path per lane.
      const float xs  = acc + bsel;
      const float xin = (g == 2) ? 2.f * xs : xs;
      const float sgm = 1.f / (1.f + expf(-xin));
      const float act = (g == 2) ? 2.f * sgm - 1.f : sgm;
      const float ai = __shfl(act, 0, 64);
      const float af = __shfl(act, 16, 64);
      const float ag = __shfl(act, 32, 64);
      const float ao = __shfl(act, 48, 64);
      cst = af * cst + ai * ag;
      const float tc = 2.f / (1.f + expf(-2.f * cst)) - 1.f;   // tanh(cst)
      const float hv = ao * tc;
      if (lane == 0) {
        if (role == 0)
          __hip_atomic_store(&g_h1[k & 1][j], pack(hv, k),
                             __ATOMIC_RELAXED, __HIP_MEMORY_SCOPE_AGENT);
        else
          __hip_atomic_store(&g_h2[(k + 1) & 1][j], pack(hv, k),
                             __ATOMIC_RELAXED, __HIP_MEMORY_SCOPE_AGENT);
      }
    }
    // no trailing barrier: double-buffered vec + per-tick barrier1 keep WAR safe
  }

  // ---- final output: out = W_out . h2(T-1) + b_out ----
  if (wg == 0 && wave == 0) {
    float acc = 0.f;
    int bud2 = 1 << 24;
#pragma unroll
    for (int e = 0; e < HDIM / 64; ++e) {
      const int idx = lane + e * 64;
      unsigned long long u;
      do {
        u = __hip_atomic_load(&g_h2[1][idx], __ATOMIC_RELAXED, __HIP_MEMORY_SCOPE_AGENT);
      } while ((unsigned)(u >> 32) != (unsigned)T_LEN && --bud2 > 0);
      acc = fmaf(W_out[idx], __uint_as_float((unsigned)u), acc);
    }
    acc += __shfl_xor(acc, 32, 64);
    acc += __shfl_xor(acc, 16, 64);
    acc += __shfl_xor(acc, 8, 64);
    acc += __shfl_xor(acc, 4, 64);
    acc += __shfl_xor(acc, 2, 64);
    acc += __shfl_xor(acc, 1, 64);
    if (lane == 0) out[0] = acc + b_out[0];
  }
}

extern "C" void kernel_launch(void* const* d_in, const int* in_sizes, int n_in,
                              void* d_out, int out_size, void* d_ws, size_t ws_size,
                              hipStream_t stream) {
  const float* x_seq = (const float*)d_in[0];
  const float* W_ih1 = (const float*)d_in[1];
  const float* W_hh1 = (const float*)d_in[2];
  const float* b_ih1 = (const float*)d_in[3];
  const float* b_hh1 = (const float*)d_in[4];
  const float* W_ih2 = (const float*)d_in[5];
  const float* W_hh2 = (const float*)d_in[6];
  const float* b_ih2 = (const float*)d_in[7];
  const float* b_hh2 = (const float*)d_in[8];
  const float* W_out = (const float*)d_in[9];
  const float* b_out = (const float*)d_in[10];
  float* out = (float*)d_out;

  hipLaunchKernelGGL(lstm_init, dim3(1), dim3(256), 0, stream);
  hipLaunchKernelGGL(lstm_main, dim3(NWG), dim3(NTHR), 0, stream,
                     x_seq, W_ih1, W_hh1, b_ih1, b_hh1,
                     W_ih2, W_hh2, b_ih2, b_hh2, W_out, b_out, out);
}